// Round 1
// baseline (256.208 us; speedup 1.0000x reference)
//
#include <hip/hip_runtime.h>
#include <math.h>

// ---- Problem constants (derived from the reference) ----
// IN0 dim = 120, HID0 dim = 360, HID1 dim = 180
// K1 = 64 * 180 = 11520
// x_out: 64 spatial x 180      -> out[0 .. 11520)
// grid1: 64 x K1 x 72          -> out[11520 .. 11520+53084160)
// radii: 8x8x8 = 512, all = 27 -> out[53095680 .. 53096192)
#define K1        11520
#define XDIM      180
#define NSP       64
#define NG        72
#define OUT1_OFF  11520
#define OUT2_OFF  (11520 + (size_t)NSP * K1 * NG)

#define INV_S32 0.17677669529663687f  // 1/sqrt(32)
#define INV_S8  0.35355339059327373f  // 1/sqrt(8)
#define INV_S16 0.25f                 // 1/sqrt(16)
#define INV_S64 0.125f                // 1/sqrt(64)

// ---------------------------------------------------------------------------
// Kernel A: per spatial point, block0 linear -> block1 linear -> x_out.
// Also writes the constant radii output and (block 0 only) the Y table
// [9 x 72] into the workspace, using the exact same sinf/cosf evaluation the
// previously-verified kernel used (bit-identical grid1 numerics).
// Grid: 64 blocks (one per spatial point), 64 threads.
// Dead inputs (verified by zero-propagation through eq_linear):
//   w2b0_* (grid0/sh0 unused), w1b1_0o/w1b1_1e/w1b1_2o (multiply exact zeros).
// ---------------------------------------------------------------------------
__global__ __launch_bounds__(64) void eq_linears_kernel(
    const float* __restrict__ x,          // [64,120]
    const float* __restrict__ w1b0_0e,    // [32,64]
    const float* __restrict__ w1b0_1o,    // [16,16]
    const float* __restrict__ w1b0_2e,    // [8,16]
    const float* __restrict__ w1b1_0e,    // [64,32]
    const float* __restrict__ w1b1_1o,    // [16,8]
    const float* __restrict__ w1b1_2e,    // [16,8]
    float* __restrict__ out,
    float* __restrict__ yws)              // workspace: [9*72] Y table
{
    __shared__ float xin[120];
    __shared__ float x1_0e[64];
    __shared__ float x1_2e[80];   // (16,5): [i*5+m]
    __shared__ float x1_1o[48];   // (16,3): [i*3+m]
    __shared__ float xout[XDIM];

    const int t = threadIdx.x;
    const int s = blockIdx.x;

    for (int f = t; f < 120; f += 64) xin[f] = x[s * 120 + f];
    for (int f = t; f < XDIM; f += 64) xout[f] = 0.0f;
    __syncthreads();

    // block0: x1_0e[i] = sum_j xin0e[j] * w1b0_0e[j,i] / sqrt(32), i<64
    {
        float acc = 0.0f;
        #pragma unroll
        for (int j = 0; j < 32; ++j) acc += xin[j] * w1b0_0e[j * 64 + t];
        x1_0e[t] = acc * INV_S32;
    }
    // block0: x1_2e[i,m] = sum_j xin2e[j,m] * w1b0_2e[j,i] / sqrt(8), i<16,m<5
    for (int e = t; e < 80; e += 64) {
        int i = e / 5, m = e % 5;
        float acc = 0.0f;
        #pragma unroll
        for (int j = 0; j < 8; ++j) acc += xin[80 + j * 5 + m] * w1b0_2e[j * 16 + i];
        x1_2e[e] = acc * INV_S8;
    }
    // block0: x1_1o[i,m] = sum_j xin1o[j,m] * w1b0_1o[j,i] / sqrt(16), i<16,m<3
    if (t < 48) {
        int i = t / 3, m = t % 3;
        float acc = 0.0f;
        #pragma unroll
        for (int j = 0; j < 16; ++j) acc += xin[32 + j * 3 + m] * w1b0_1o[j * 16 + i];
        x1_1o[t] = acc * INV_S16;
    }
    __syncthreads();

    // block1: s0e[o] = sum_i x1_0e[i] * w1b1_0e[i,o] / sqrt(64), o<32
    if (t < 32) {
        float acc = 0.0f;
        #pragma unroll
        for (int i = 0; i < 64; ++i) acc += x1_0e[i] * w1b1_0e[i * 32 + t];
        xout[t] = acc * INV_S64;
    }
    // block1: s2e[o,m] = sum_i x1_2e[i,m] * w1b1_2e[i,o] / sqrt(16), o<8,m<5
    if (t < 40) {
        int o = t / 5, m = t % 5;
        float acc = 0.0f;
        #pragma unroll
        for (int i = 0; i < 16; ++i) acc += x1_2e[i * 5 + m] * w1b1_2e[i * 8 + o];
        xout[96 + t] = acc * INV_S16;
    }
    // block1: s1o[o,m] = sum_i x1_1o[i,m] * w1b1_1o[i,o] / sqrt(16), o<8,m<3
    if (t < 24) {
        int o = t / 3, m = t % 3;
        float acc = 0.0f;
        #pragma unroll
        for (int i = 0; i < 16; ++i) acc += x1_1o[i * 3 + m] * w1b1_1o[i * 8 + o];
        xout[136 + t] = acc * INV_S16;
    }
    __syncthreads();

    for (int f = t; f < XDIM; f += 64) out[s * XDIM + f] = xout[f];

    // radii: constant 27 everywhere (|g-center| = sqrt(0.75) for all fine
    // points; nearest bin of linspace(0,2,64) is index 27). Output dtype is
    // float32 (tuple promoted), so write 27.0f.
    if (t < 8) out[OUT2_OFF + (size_t)s * 8 + t] = 27.0f;

    // Y table -> workspace (block 0 only). Same math as the verified kernel.
    if (s == 0) {
        for (int g = t; g < NG; g += 64) {
            int bi = g / 12, ai = g % 12;
            float bb = (bi + 0.5f) * (float)(M_PI / 6.0);
            float aa = (float)ai * (float)(M_PI / 6.0);   // 2*pi/12
            float sb = sinf(bb), cb = cosf(bb);
            float sa = sinf(aa), ca = cosf(aa);
            float sx = sb * ca, sy = sb * sa, sz = cb;
            const float s3  = 1.7320508075688772f;
            const float s15 = 3.872983346207417f;
            const float s5  = 2.23606797749979f;
            yws[0 * NG + g] = 1.0f;
            yws[1 * NG + g] = s3 * sx;
            yws[2 * NG + g] = s3 * sy;
            yws[3 * NG + g] = s3 * sz;
            yws[4 * NG + g] = s15 * sx * sy;
            yws[5 * NG + g] = s15 * sy * sz;
            yws[6 * NG + g] = 0.5f * s5 * (3.0f * sz * sz - 1.0f);
            yws[7 * NG + g] = s15 * sx * sz;
            yws[8 * NG + g] = 0.5f * s15 * (sx * sx - sy * sy);
        }
    }
}

// ---------------------------------------------------------------------------
// Kernel B (restructured): grid1[s,k,g] = sum_c coeff[s,k,c] * Y[c,g]
// - Each thread owns ONE k-row: its c[9] stays in registers (no coeff LDS).
// - Y read from workspace with wave-uniform indices -> scalar (SMEM) loads;
//   inner loop is pure v_fma with one SGPR operand. Zero LDS for Y.
// - LDS used ONLY to transpose per-thread rows into contiguous spans:
//   2 rounds of 128 full rows (128 x 76-padded f32 = 38.9 KB), each drained
//   by all 256 threads as perfectly contiguous float4 stores.
// Grid: (45, 64) blocks, 256 threads.
// ---------------------------------------------------------------------------
#define STRIDE 76   // 72 + 4 pad: ds_write_b128 row stride -> ~2-way banks (free)

__global__ __launch_bounds__(256) void grid1_kernel(
    const float* __restrict__ Yg,        // [9*72] from workspace
    const float* __restrict__ w2b1_0e,   // [32,K1]
    const float* __restrict__ w2b1_1o,   // [8,K1]
    const float* __restrict__ w2b1_2e,   // [8,K1]
    const float* __restrict__ xall,      // x_out region of out (disjoint from writes)
    float* __restrict__ outg)            // out base
{
    __shared__ float stage[128 * STRIDE];   // 38912 B

    const int t = threadIdx.x;
    const int s = blockIdx.y;
    const int k = blockIdx.x * 256 + t;
    const float* xs = xall + (size_t)s * XDIM;   // uniform indices -> s_load

    // Phase 1: per-thread coefficients c[9] for this k (weights coalesced
    // across lanes: consecutive k).
    float c[9];
    {
        float a0 = 0.0f;
        #pragma unroll
        for (int i = 0; i < 32; ++i) a0 += xs[i] * w2b1_0e[i * K1 + k];
        c[0] = a0 * INV_S32;
        #pragma unroll
        for (int m = 0; m < 3; ++m) {
            float a = 0.0f;
            #pragma unroll
            for (int i = 0; i < 8; ++i) a += xs[136 + i * 3 + m] * w2b1_1o[i * K1 + k];
            c[1 + m] = a * INV_S8;
        }
        #pragma unroll
        for (int m = 0; m < 5; ++m) {
            float a = 0.0f;
            #pragma unroll
            for (int i = 0; i < 8; ++i) a += xs[96 + i * 5 + m] * w2b1_2e[i * K1 + k];
            c[4 + m] = a * INV_S8;
        }
    }

    float* outbase = outg + OUT1_OFF
                   + ((size_t)s * K1 + (size_t)blockIdx.x * 256) * NG;
    const int lr   = t & 127;
    const int half = t >> 7;    // wave-uniform (waves 0-1 vs 2-3)

    for (int r = 0; r < 2; ++r) {
        if (half == r) {
            // Compute this thread's full 72-float row. Y loads are
            // wave-uniform (loop indices only) -> scalar loads; FMA takes the
            // Y component as an SGPR operand (1 SGPR/inst: legal).
            #pragma unroll
            for (int gq = 0; gq < 18; ++gq) {
                float4 acc = make_float4(0.0f, 0.0f, 0.0f, 0.0f);
                #pragma unroll
                for (int cc = 0; cc < 9; ++cc) {
                    const float4 yv = *(const float4*)(Yg + cc * NG + gq * 4);
                    acc.x += c[cc] * yv.x;
                    acc.y += c[cc] * yv.y;
                    acc.z += c[cc] * yv.z;
                    acc.w += c[cc] * yv.w;
                }
                *(float4*)(&stage[lr * STRIDE + gq * 4]) = acc;
            }
        }
        __syncthreads();
        // Drain: 128 rows x 72 floats = 2304 float4, perfectly contiguous in
        // global (float4 index f4 maps linearly to outbase + r*9216 + f4*4).
        #pragma unroll
        for (int q = 0; q < 9; ++q) {
            const int f4 = t + q * 256;
            const int kk = f4 / 18;
            const int gq = f4 - kk * 18;
            const float4 v = *(const float4*)(&stage[kk * STRIDE + gq * 4]);
            *(float4*)(outbase + (size_t)r * 9216 + (size_t)f4 * 4) = v;
        }
        __syncthreads();
    }
}

extern "C" void kernel_launch(void* const* d_in, const int* in_sizes, int n_in,
                              void* d_out, int out_size, void* d_ws, size_t ws_size,
                              hipStream_t stream) {
    const float* x        = (const float*)d_in[0];
    const float* w1b0_0e  = (const float*)d_in[1];
    const float* w1b0_1o  = (const float*)d_in[2];
    const float* w1b0_2e  = (const float*)d_in[3];
    // d_in[4..6] = w2b0_* : dead (grid0/sh0 unused by the reference outputs)
    const float* w1b1_0e  = (const float*)d_in[7];
    // d_in[8] w1b1_0o, d_in[9] w1b1_1e, d_in[12] w1b1_2o: multiply exact zeros -> dead
    const float* w1b1_1o  = (const float*)d_in[10];
    const float* w1b1_2e  = (const float*)d_in[11];
    const float* w2b1_0e  = (const float*)d_in[13];
    const float* w2b1_1o  = (const float*)d_in[14];
    const float* w2b1_2e  = (const float*)d_in[15];
    float* out = (float*)d_out;
    float* yws = (float*)d_ws;   // 9*72 floats = 2592 B

    eq_linears_kernel<<<dim3(NSP), dim3(64), 0, stream>>>(
        x, w1b0_0e, w1b0_1o, w1b0_2e, w1b1_0e, w1b1_1o, w1b1_2e, out, yws);

    grid1_kernel<<<dim3(K1 / 256, NSP), dim3(256), 0, stream>>>(
        yws, w2b1_0e, w2b1_1o, w2b1_2e, out, out);
}